// Round 17
// baseline (54.956 us; speedup 1.0000x reference)
//
#include <hip/hip_runtime.h>

#define PIMG 1024   // H*W = 32*32
#define CCH  128    // channels
#define KG   68     // clusters incl. ghost
#define KR   64     // real clusters
#define T1   32     // pixels per block
#define XP   36     // xs pitch
#define LP   40     // lg pitch (b128-aligned; all patterns <=2-way)

typedef float f4v __attribute__((ext_vector_type(4)));

// ---------------- Fused kernel v6: LDS-lean logit phase ---------------------
// grid: 8n * 32 tiles * 2 kh = 512 blocks (2/CU), 512 threads (8 waves).
// v5 head, but logits use 128 tasks x (4..5 k) so each xs b128 read feeds
// 4-5 clusters: LDS-pipe wave-instrs halve (the measured 5.3us head term).
// Store phase: xn in regs, a4 broadcast, 8x128B segments (R13 proven).
__global__ __launch_bounds__(512) void nv_fused_kernel(
    const float* __restrict__ x,          // [N,128,1024]
    const float* __restrict__ conv_w,     // [68,128]
    const float* __restrict__ centroids,  // [68,128]
    float* __restrict__ out,              // [N,64,128,1024]
    float* __restrict__ sa_out)           // [N,68,1024]
{
    __shared__ float xs[CCH * XP];   // raw x tile [c][pix]   18.4 KB
    __shared__ float lg[KG * LP];    // logits -> exp         10.9 KB
    __shared__ float red[16 * T1];   // reduction scratch      2 KB
    __shared__ float rn_l[T1];
    __shared__ float is_l[T1];

    const int t    = threadIdx.x;
    const int b    = blockIdx.x;
    const int kh   = b & 1;
    const int tile = (b >> 1) & 31;
    const int n    = b >> 6;
    const int p0   = tile * T1;
    const int k0   = kh * 32;        // out k-half

    // ---- A: stage x tile + fused norm partials ----
    {
        const int pix = t & 31, cg = t >> 5;   // cg: 0..15
        const float* xb = x + (size_t)n * (CCH * PIMG) + p0 + pix;
        float ss = 0.f;
        #pragma unroll
        for (int j = 0; j < 8; ++j) {
            int c = cg + 16 * j;
            float v = xb[(size_t)c * PIMG];
            xs[c * XP + pix] = v;
            ss += v * v;
        }
        red[cg * T1 + pix] = ss;
    }
    __syncthreads();
    // ---- B: rn ----
    if (t < T1) {
        float s = 0.f;
        #pragma unroll
        for (int q = 0; q < 16; ++q) s += red[q * T1 + t];
        rn_l[t] = 1.0f / fmaxf(sqrtf(s), 1e-12f);
    }
    __syncthreads();

    // ---- C: logits = (sum x*w) * rn ----
    // 128 tasks = (g of 8, q of 16); k = q+16j (j=0..3) + tail k=64+q (q<4).
    // Each xs b128 read feeds 4-5 clusters -> ~half the LDS wave-instrs of v5.
    if (t < 128) {
        const int g = t & 7, q = t >> 3;     // q: 0..15
        const float* xr = xs + g * 4;
        const float* w0 = conv_w + q * CCH;
        const float* w1 = conv_w + (q + 16) * CCH;
        const float* w2 = conv_w + (q + 32) * CCH;
        const float* w3 = conv_w + (q + 48) * CCH;
        const float* w4 = conv_w + ((q < 4 ? 64 + q : q)) * CCH; // dummy if q>=4
        f4v a0 = {0,0,0,0}, a1 = {0,0,0,0}, a2 = {0,0,0,0},
            a3 = {0,0,0,0}, a4 = {0,0,0,0};
        #pragma unroll 8
        for (int c0 = 0; c0 < CCH; c0 += 4) {
            f4v x0 = *(const f4v*)(xr + (c0 + 0) * XP);
            f4v x1 = *(const f4v*)(xr + (c0 + 1) * XP);
            f4v x2 = *(const f4v*)(xr + (c0 + 2) * XP);
            f4v x3 = *(const f4v*)(xr + (c0 + 3) * XP);
            f4v v0 = *(const f4v*)(w0 + c0);
            f4v v1 = *(const f4v*)(w1 + c0);
            f4v v2 = *(const f4v*)(w2 + c0);
            f4v v3 = *(const f4v*)(w3 + c0);
            f4v v4 = *(const f4v*)(w4 + c0);
            a0 += x0 * v0.x; a0 += x1 * v0.y; a0 += x2 * v0.z; a0 += x3 * v0.w;
            a1 += x0 * v1.x; a1 += x1 * v1.y; a1 += x2 * v1.z; a1 += x3 * v1.w;
            a2 += x0 * v2.x; a2 += x1 * v2.y; a2 += x2 * v2.z; a2 += x3 * v2.w;
            a3 += x0 * v3.x; a3 += x1 * v3.y; a3 += x2 * v3.z; a3 += x3 * v3.w;
            a4 += x0 * v4.x; a4 += x1 * v4.y; a4 += x2 * v4.z; a4 += x3 * v4.w;
        }
        f4v r4 = *(const f4v*)(rn_l + g * 4);
        *(f4v*)(lg + q * LP + g * 4)        = a0 * r4;
        *(f4v*)(lg + (q + 16) * LP + g * 4) = a1 * r4;
        *(f4v*)(lg + (q + 32) * LP + g * 4) = a2 * r4;
        *(f4v*)(lg + (q + 48) * LP + g * 4) = a3 * r4;
        if (q < 4)
            *(f4v*)(lg + (q + 64) * LP + g * 4) = a4 * r4;
    }
    __syncthreads();

    // ---- D: exp + sum (no max-subtract; |logit| < 1) ----
    {
        const int pix = t & 31, q = t >> 5;
        float s = 0.f;
        for (int k = q; k < KG; k += 16) {
            float e = expf(lg[k * LP + pix]);
            lg[k * LP + pix] = e;
            s += e;
        }
        red[q * T1 + pix] = s;
    }
    __syncthreads();
    // ---- E: is = 1/sum ----
    if (t < T1) {
        float s = 0.f;
        #pragma unroll
        for (int q = 0; q < 16; ++q) s += red[q * T1 + t];
        is_l[t] = 1.0f / s;
    }
    __syncthreads();

    // ---- F: sa write (this kh's 34-k half) + store phase ----
    {
        const int half = KG / 2;   // 34
        for (int i = t; i < half * T1; i += 512) {
            int k = kh * half + (i >> 5), pix = i & 31;
            sa_out[((size_t)n * KG + k) * PIMG + p0 + pix] =
                lg[k * LP + pix] * is_l[pix];
        }
    }
    {
        const int g  = t & 7;        // pix4 group
        const int cp = t >> 3;       // c-pair: c = 2cp, 2cp+1
        const int c0 = 2 * cp, c1 = 2 * cp + 1;
        const f4v rn4 = *(const f4v*)(rn_l + g * 4);
        const f4v is4 = *(const f4v*)(is_l + g * 4);
        const f4v xn0 = *(const f4v*)(xs + c0 * XP + g * 4) * rn4;
        const f4v xn1 = *(const f4v*)(xs + c1 * XP + g * 4) * rn4;
        const float* cb = centroids + (size_t)k0 * CCH;
        float* ob = out + (((size_t)n * KR + k0) * CCH) * PIMG + p0 + g * 4;

        #pragma unroll 4
        for (int k = 0; k < 32; ++k) {
            f4v a4 = *(const f4v*)(lg + (k0 + k) * LP + g * 4) * is4;
            float ce0 = cb[k * CCH + c0];
            float ce1 = cb[k * CCH + c1];
            *(f4v*)(ob + ((size_t)k * CCH + c0) * PIMG) = (xn0 - ce0) * a4;
            *(f4v*)(ob + ((size_t)k * CCH + c1) * PIMG) = (xn1 - ce1) * a4;
        }
    }
}

extern "C" void kernel_launch(void* const* d_in, const int* in_sizes, int n_in,
                              void* d_out, int out_size, void* d_ws, size_t ws_size,
                              hipStream_t stream) {
    const float* x         = (const float*)d_in[0];
    const float* conv_w    = (const float*)d_in[1];
    const float* centroids = (const float*)d_in[2];

    const int N = in_sizes[0] / (CCH * PIMG);   // 8

    float* out    = (float*)d_out;
    float* sa_out = out + (size_t)N * KR * CCH * PIMG;  // second tuple element

    nv_fused_kernel<<<N * 32 * 2, 512, 0, stream>>>(
        x, conv_w, centroids, out, sa_out);
}

// Round 18
// 52.274 us; speedup vs baseline: 1.0513x; 1.0513x over previous
//
#include <hip/hip_runtime.h>

#define PIMG 1024   // H*W = 32*32
#define CCH  128    // channels
#define KG   68     // clusters incl. ghost
#define KR   64     // real clusters
#define T1   32     // pixels per block
#define XP   36     // xs pitch
#define LP   40     // lg pitch (b128-aligned; all patterns <=2-way)

typedef float f4v __attribute__((ext_vector_type(4)));

// ---------------- Fused kernel v5 (R16 best, reverted from v6) --------------
// grid: 8n * 32 tiles * 2 kh = 512 blocks (2/CU), 512 threads (8 waves).
// Head: fused stage+norm, no max-subtract (|logit| < 1 by Cauchy-Schwarz),
// rn folded into logit epilogue + store regs, is-mul at consumption.
// Store phase: xn in regs, a4 broadcast, 8x128B segments. 5 barriers.
__global__ __launch_bounds__(512) void nv_fused_kernel(
    const float* __restrict__ x,          // [N,128,1024]
    const float* __restrict__ conv_w,     // [68,128]
    const float* __restrict__ centroids,  // [68,128]
    float* __restrict__ out,              // [N,64,128,1024]
    float* __restrict__ sa_out)           // [N,68,1024]
{
    __shared__ float xs[CCH * XP];   // raw x tile [c][pix]   18.4 KB
    __shared__ float lg[KG * LP];    // logits -> exp         10.9 KB
    __shared__ float red[16 * T1];   // reduction scratch      2 KB
    __shared__ float rn_l[T1];
    __shared__ float is_l[T1];

    const int t    = threadIdx.x;
    const int b    = blockIdx.x;
    const int kh   = b & 1;
    const int tile = (b >> 1) & 31;
    const int n    = b >> 6;
    const int p0   = tile * T1;
    const int k0   = kh * 32;        // out k-half

    // ---- A: stage x tile + fused norm partials ----
    {
        const int pix = t & 31, cg = t >> 5;   // cg: 0..15
        const float* xb = x + (size_t)n * (CCH * PIMG) + p0 + pix;
        float ss = 0.f;
        #pragma unroll
        for (int j = 0; j < 8; ++j) {
            int c = cg + 16 * j;
            float v = xb[(size_t)c * PIMG];
            xs[c * XP + pix] = v;
            ss += v * v;
        }
        red[cg * T1 + pix] = ss;
    }
    __syncthreads();
    // ---- B: rn ----
    if (t < T1) {
        float s = 0.f;
        #pragma unroll
        for (int q = 0; q < 16; ++q) s += red[q * T1 + t];
        rn_l[t] = 1.0f / fmaxf(sqrtf(s), 1e-12f);
    }
    __syncthreads();

    // ---- C: logits = (sum x*w) * rn; 272 tasks (g of 8, q of 34) ----
    if (t < 272) {
        const int g = t & 7, q = t >> 3;     // q: 0..33
        const float* xr = xs + g * 4;
        const float* w0 = conv_w + q * CCH;
        const float* w1 = conv_w + (q + 34) * CCH;
        f4v a0 = {0,0,0,0}, a1 = {0,0,0,0};
        #pragma unroll 8
        for (int c0 = 0; c0 < CCH; c0 += 4) {
            f4v x0 = *(const f4v*)(xr + (c0 + 0) * XP);
            f4v x1 = *(const f4v*)(xr + (c0 + 1) * XP);
            f4v x2 = *(const f4v*)(xr + (c0 + 2) * XP);
            f4v x3 = *(const f4v*)(xr + (c0 + 3) * XP);
            f4v v0 = *(const f4v*)(w0 + c0);
            f4v v1 = *(const f4v*)(w1 + c0);
            a0 += x0 * v0.x; a0 += x1 * v0.y; a0 += x2 * v0.z; a0 += x3 * v0.w;
            a1 += x0 * v1.x; a1 += x1 * v1.y; a1 += x2 * v1.z; a1 += x3 * v1.w;
        }
        f4v r4 = *(const f4v*)(rn_l + g * 4);
        *(f4v*)(lg + q * LP + g * 4)        = a0 * r4;
        *(f4v*)(lg + (q + 34) * LP + g * 4) = a1 * r4;
    }
    __syncthreads();

    // ---- D: exp + sum (no max-subtract; |logit| < 1) ----
    {
        const int pix = t & 31, q = t >> 5;
        float s = 0.f;
        for (int k = q; k < KG; k += 16) {
            float e = expf(lg[k * LP + pix]);
            lg[k * LP + pix] = e;
            s += e;
        }
        red[q * T1 + pix] = s;
    }
    __syncthreads();
    // ---- E: is = 1/sum ----
    if (t < T1) {
        float s = 0.f;
        #pragma unroll
        for (int q = 0; q < 16; ++q) s += red[q * T1 + t];
        is_l[t] = 1.0f / s;
    }
    __syncthreads();

    // ---- F: sa write (this kh's 34-k half) + store phase ----
    {
        const int half = KG / 2;   // 34
        for (int i = t; i < half * T1; i += 512) {
            int k = kh * half + (i >> 5), pix = i & 31;
            sa_out[((size_t)n * KG + k) * PIMG + p0 + pix] =
                lg[k * LP + pix] * is_l[pix];
        }
    }
    {
        const int g  = t & 7;        // pix4 group
        const int cp = t >> 3;       // c-pair: c = 2cp, 2cp+1
        const int c0 = 2 * cp, c1 = 2 * cp + 1;
        const f4v rn4 = *(const f4v*)(rn_l + g * 4);
        const f4v is4 = *(const f4v*)(is_l + g * 4);
        const f4v xn0 = *(const f4v*)(xs + c0 * XP + g * 4) * rn4;
        const f4v xn1 = *(const f4v*)(xs + c1 * XP + g * 4) * rn4;
        const float* cb = centroids + (size_t)k0 * CCH;
        float* ob = out + (((size_t)n * KR + k0) * CCH) * PIMG + p0 + g * 4;

        #pragma unroll 4
        for (int k = 0; k < 32; ++k) {
            f4v a4 = *(const f4v*)(lg + (k0 + k) * LP + g * 4) * is4;
            float ce0 = cb[k * CCH + c0];
            float ce1 = cb[k * CCH + c1];
            *(f4v*)(ob + ((size_t)k * CCH + c0) * PIMG) = (xn0 - ce0) * a4;
            *(f4v*)(ob + ((size_t)k * CCH + c1) * PIMG) = (xn1 - ce1) * a4;
        }
    }
}

extern "C" void kernel_launch(void* const* d_in, const int* in_sizes, int n_in,
                              void* d_out, int out_size, void* d_ws, size_t ws_size,
                              hipStream_t stream) {
    const float* x         = (const float*)d_in[0];
    const float* conv_w    = (const float*)d_in[1];
    const float* centroids = (const float*)d_in[2];

    const int N = in_sizes[0] / (CCH * PIMG);   // 8

    float* out    = (float*)d_out;
    float* sa_out = out + (size_t)N * KR * CCH * PIMG;  // second tuple element

    nv_fused_kernel<<<N * 32 * 2, 512, 0, stream>>>(
        x, conv_w, centroids, out, sa_out);
}